// Round 1
// baseline (387.119 us; speedup 1.0000x reference)
//
#include <hip/hip_runtime.h>

typedef _Float16 f16;
typedef _Float16 f16x8 __attribute__((ext_vector_type(8)));
typedef _Float16 f16x4 __attribute__((ext_vector_type(4)));
typedef float f32x4 __attribute__((ext_vector_type(4)));

__device__ __forceinline__ f32x4 mfma16(f16x8 a, f16x8 b, f32x4 c) {
    return __builtin_amdgcn_mfma_f32_16x16x32_f16(a, b, c, 0, 0, 0);
}

// Stage a 128x64 (rows x K) tile from global (row stride 1024 elements) into LDS
// as fp16 with 16B-chunk XOR swizzle: chunk c of row r lands at c ^ (r&7).
// 256 threads, 4 chunks (8 halves) per thread.
template <typename T>
__device__ __forceinline__ void stage128(f16* dst, const T* src, int tid) {
#pragma unroll
    for (int i = 0; i < 4; ++i) {
        int id = tid + i * 256;
        int row = id >> 3, c = id & 7;
        const T* p = src + row * 1024 + c * 8;
        f16x8 h;
        if constexpr (sizeof(T) == 4) {
            f32x4 f0 = *(const f32x4*)p;
            f32x4 f1 = *(const f32x4*)(p + 4);
            h[0] = (f16)f0[0]; h[1] = (f16)f0[1]; h[2] = (f16)f0[2]; h[3] = (f16)f0[3];
            h[4] = (f16)f1[0]; h[5] = (f16)f1[1]; h[6] = (f16)f1[2]; h[7] = (f16)f1[3];
        } else {
            h = *(const f16x8*)p;
        }
        *(f16x8*)&dst[row * 64 + ((c ^ (row & 7)) << 3)] = h;
    }
}

// C[m][n] = sum_k A[m*1024+k] * B[n*1024+k] + bias   (K = 1024 fixed)
// 128x128 tile per block, 4 waves in 2x2, 64x64 per wave, 16x16x32 f16 MFMA.
template <typename TA, typename TB, bool OUT16, bool BIASROW>
__global__ __launch_bounds__(256, 2) void gemm128(const TA* __restrict__ A,
                                                  const TB* __restrict__ B,
                                                  const float* __restrict__ bias,
                                                  void* __restrict__ Cout, int ldo) {
    __shared__ __align__(16) f16 As[128 * 64];
    __shared__ __align__(16) f16 Bs[128 * 64];
    int tid = threadIdx.x;
    int lane = tid & 63, w = tid >> 6;
    int wm = w & 1, wn = w >> 1;
    int l15 = lane & 15, quad = lane >> 4;
    long m0 = (long)blockIdx.x * 128;
    long n0 = (long)blockIdx.y * 128;

    f32x4 acc[4][4] = {};

    for (int k0 = 0; k0 < 1024; k0 += 64) {
        __syncthreads();
        stage128<TA>(As, A + m0 * 1024 + k0, tid);
        stage128<TB>(Bs, B + n0 * 1024 + k0, tid);
        __syncthreads();
#pragma unroll
        for (int ks = 0; ks < 2; ++ks) {
            int cc = (ks * 4 + quad) ^ (l15 & 7);
            f16x8 af[4], bf[4];
#pragma unroll
            for (int t = 0; t < 4; ++t) {
                af[t] = *(const f16x8*)&As[(wm * 64 + t * 16 + l15) * 64 + cc * 8];
                bf[t] = *(const f16x8*)&Bs[(wn * 64 + t * 16 + l15) * 64 + cc * 8];
            }
#pragma unroll
            for (int i = 0; i < 4; ++i)
#pragma unroll
                for (int j = 0; j < 4; ++j)
                    acc[i][j] = mfma16(af[i], bf[j], acc[i][j]);
        }
    }

    // C/D layout: col = lane&15, row = quad*4 + reg
#pragma unroll
    for (int i = 0; i < 4; ++i) {
        int mrow = wm * 64 + i * 16 + quad * 4;
#pragma unroll
        for (int j = 0; j < 4; ++j) {
            int ncol = wn * 64 + j * 16 + l15;
            long gn = n0 + ncol;
#pragma unroll
            for (int r = 0; r < 4; ++r) {
                long gm = m0 + mrow + r;
                float v = acc[i][j][r] + (BIASROW ? bias[gm] : bias[gn]);
                if constexpr (OUT16)
                    ((f16*)Cout)[gm * ldo + gn] = (f16)v;
                else
                    ((float*)Cout)[gm * ldo + gn] = v;
            }
        }
    }
}

// Attention: per block one (n, h, 128-row Q tile). Iterates 32 K-tiles of 64.
// No max-subtraction (logits bounded ~|0.7|): O_unnorm = sum exp(s)*v, divide by rowsum.
__global__ __launch_bounds__(256, 2) void attn128(const f16* __restrict__ Qp,
                                                  const f16* __restrict__ Kp,
                                                  const f16* __restrict__ Vt,
                                                  f16* __restrict__ Op) {
    __shared__ __align__(16) f16 Qs[128 * 64];
    __shared__ __align__(16) f16 Ks[64 * 64];
    __shared__ __align__(16) f16 Vs[64 * 64];
    __shared__ __align__(16) f16 Ps[128 * 64];
    __shared__ float lsi[128];

    int tid = threadIdx.x;
    int lane = tid & 63, w = tid >> 6;
    int l15 = lane & 15, quad = lane >> 4;
    int qt = blockIdx.x;  // 0..15
    int nh = blockIdx.y;  // 0..63
    int nb = nh >> 4, h = nh & 15;
    long tok0 = (long)nb * 2048;

    // stage Q tile once: rows q, 64 d each
    {
        const f16* src = Qp + (tok0 + qt * 128) * 1024 + h * 64;
#pragma unroll
        for (int i = 0; i < 4; ++i) {
            int id = tid + i * 256;
            int row = id >> 3, c = id & 7;
            f16x8 hv = *(const f16x8*)&src[row * 1024 + c * 8];
            *(f16x8*)&Qs[row * 64 + ((c ^ (row & 7)) << 3)] = hv;
        }
    }

    f32x4 oacc[2][4] = {};
    float rsum[2] = {0.f, 0.f};

    for (int kt = 0; kt < 32; ++kt) {
        __syncthreads();
        {
            const f16* ksrc = Kp + (tok0 + kt * 64) * 1024 + h * 64;
            const f16* vsrc = Vt + (long)(h * 64) * 8192 + tok0 + kt * 64;
#pragma unroll
            for (int i = 0; i < 2; ++i) {
                int id = tid + i * 256;
                int row = id >> 3, c = id & 7;
                f16x8 hv = *(const f16x8*)&ksrc[row * 1024 + c * 8];
                *(f16x8*)&Ks[row * 64 + ((c ^ (row & 7)) << 3)] = hv;
                f16x8 vv = *(const f16x8*)&vsrc[(long)row * 8192 + c * 8];
                *(f16x8*)&Vs[row * 64 + ((c ^ (row & 7)) << 3)] = vv;
            }
        }
        __syncthreads();

        // S^T tile = K(64 k-rows) x Q^T : D[i = k][j = q]; wave w owns q cols [w*32, w*32+32)
        f32x4 sacc[4][2] = {};
#pragma unroll
        for (int ks = 0; ks < 2; ++ks) {
            int cc = (ks * 4 + quad) ^ (l15 & 7);
            f16x8 af[4], bf[2];
#pragma unroll
            for (int t = 0; t < 4; ++t)
                af[t] = *(const f16x8*)&Ks[(t * 16 + l15) * 64 + cc * 8];
#pragma unroll
            for (int j = 0; j < 2; ++j)
                bf[j] = *(const f16x8*)&Qs[(w * 32 + j * 16 + l15) * 64 + cc * 8];
#pragma unroll
            for (int i = 0; i < 4; ++i)
#pragma unroll
                for (int j = 0; j < 2; ++j)
                    sacc[i][j] = mfma16(af[i], bf[j], sacc[i][j]);
        }

        // exp, rowsum partials, pack P (4 contiguous k per lane -> b64 write)
#pragma unroll
        for (int i = 0; i < 4; ++i) {
#pragma unroll
            for (int j = 0; j < 2; ++j) {
                f16x4 ph;
                float s = 0.f;
#pragma unroll
                for (int r = 0; r < 4; ++r) {
                    float p = __expf(sacc[i][j][r] * 0.03125f);  // 1/sqrt(1024)
                    s += p;
                    ph[r] = (f16)p;
                }
                rsum[j] += s;
                int q = w * 32 + j * 16 + l15;
                int kl = i * 16 + quad * 4;
                int c = kl >> 3;
                *(f16x4*)&Ps[q * 64 + ((c ^ (q & 7)) << 3) + (kl & 7)] = ph;
            }
        }
        __syncthreads();

        // O += P(q rows, k) x V(d rows, k)^T : D[q][d]
#pragma unroll
        for (int ks = 0; ks < 2; ++ks) {
            int cc = (ks * 4 + quad) ^ (l15 & 7);
            f16x8 af[2], bf[4];
#pragma unroll
            for (int i = 0; i < 2; ++i)
                af[i] = *(const f16x8*)&Ps[(w * 32 + i * 16 + l15) * 64 + cc * 8];
#pragma unroll
            for (int j = 0; j < 4; ++j)
                bf[j] = *(const f16x8*)&Vs[(j * 16 + l15) * 64 + cc * 8];
#pragma unroll
            for (int i = 0; i < 2; ++i)
#pragma unroll
                for (int j = 0; j < 4; ++j)
                    oacc[i][j] = mfma16(af[i], bf[j], oacc[i][j]);
        }
    }

    // reduce rowsums across quads (same q lives in lanes l, l^16, l^32, l^48)
#pragma unroll
    for (int j = 0; j < 2; ++j) {
        rsum[j] += __shfl_xor(rsum[j], 16, 64);
        rsum[j] += __shfl_xor(rsum[j], 32, 64);
    }
    if (lane < 16) {
        lsi[w * 32 + lane] = 1.0f / rsum[0];
        lsi[w * 32 + 16 + lane] = 1.0f / rsum[1];
    }
    __syncthreads();

    long otok = tok0 + (long)qt * 128;
#pragma unroll
    for (int i = 0; i < 2; ++i) {
        int qrow = w * 32 + i * 16 + quad * 4;
#pragma unroll
        for (int j = 0; j < 4; ++j) {
            int d = j * 16 + l15;
#pragma unroll
            for (int r = 0; r < 4; ++r) {
                float v = oacc[i][j][r] * lsi[qrow + r];
                Op[(otok + qrow + r) * 1024 + h * 64 + d] = (f16)v;
            }
        }
    }
}

// Convert the four 1024x1024 fp32 weight matrices to fp16 (Wq,Wk,Wv,Wo packed).
__global__ void cvt_weights(const float* __restrict__ a, const float* __restrict__ b,
                            const float* __restrict__ c, const float* __restrict__ d,
                            f16* __restrict__ out) {
    int id = blockIdx.x * 256 + threadIdx.x;  // 1M threads, 4 floats each
    int m = id >> 18;                         // 262144 float4 per matrix
    const float* s = (m == 0) ? a : (m == 1) ? b : (m == 2) ? c : d;
    long off = (long)(id & 262143) * 4;
    f32x4 v = *(const f32x4*)(s + off);
    f16x4 h;
    h[0] = (f16)v[0]; h[1] = (f16)v[1]; h[2] = (f16)v[2]; h[3] = (f16)v[3];
    *(f16x4*)&out[(long)m * 1048576 + off] = h;
}

extern "C" void kernel_launch(void* const* d_in, const int* in_sizes, int n_in,
                              void* d_out, int out_size, void* d_ws, size_t ws_size,
                              hipStream_t stream) {
    const float* q  = (const float*)d_in[0];
    const float* k  = (const float*)d_in[1];
    const float* v  = (const float*)d_in[2];
    // d_in[3] padding_mask, d_in[4] sequence_mask: no effect in reference
    const float* Wq = (const float*)d_in[5];
    const float* bq = (const float*)d_in[6];
    const float* Wk = (const float*)d_in[7];
    const float* bk = (const float*)d_in[8];
    const float* Wv = (const float*)d_in[9];
    const float* bv = (const float*)d_in[10];
    const float* Wo = (const float*)d_in[11];
    const float* bo = (const float*)d_in[12];

    char* ws = (char*)d_ws;
    f16* wh = (f16*)ws;                        // 4 x 1M fp16 = 8 MB
    f16* Qp = (f16*)(ws + (8L << 20));         // [8192][1024] fp16, 16 MB
    f16* Kp = (f16*)(ws + (24L << 20));        // 16 MB
    f16* Vt = (f16*)(ws + (40L << 20));        // [1024 e][8192 tok] fp16, 16 MB
    f16* Op = (f16*)(ws + (56L << 20));        // [8192][1024] fp16, 16 MB (total 72 MB)

    cvt_weights<<<4096, 256, 0, stream>>>(Wq, Wk, Wv, Wo, wh);

    // Qp = q @ Wq^T + bq ; Kp = k @ Wk^T + bk   (fp16 out, [m][e])
    gemm128<float, f16, true, false><<<dim3(64, 8), 256, 0, stream>>>(q, wh, bq, Qp, 1024);
    gemm128<float, f16, true, false><<<dim3(64, 8), 256, 0, stream>>>(k, wh + 1048576, bk, Kp, 1024);
    // Vt = (v @ Wv^T + bv)^T : computed as Wv x v^T -> [e][tok] (bias per output row)
    gemm128<f16, float, true, true><<<dim3(8, 64), 256, 0, stream>>>(wh + 2097152, v, bv, Vt, 8192);

    attn128<<<dim3(16, 64), 256, 0, stream>>>(Qp, Kp, Vt, Op);

    // out = Op @ Wo^T + bo  (fp32 out)
    gemm128<f16, f16, false, false><<<dim3(64, 8), 256, 0, stream>>>(Op, wh + 3145728, bo, (float*)d_out, 1024);
}

// Round 3
// 343.179 us; speedup vs baseline: 1.1280x; 1.1280x over previous
//
#include <hip/hip_runtime.h>
#include <stdint.h>

typedef _Float16 f16;
typedef _Float16 f16x8 __attribute__((ext_vector_type(8)));
typedef _Float16 f16x4 __attribute__((ext_vector_type(4)));
typedef _Float16 f16x2 __attribute__((ext_vector_type(2)));
typedef __fp16 h16x2 __attribute__((ext_vector_type(2)));
typedef float f32x4 __attribute__((ext_vector_type(4)));

__device__ __forceinline__ f32x4 mfma16(f16x8 a, f16x8 b, f32x4 c) {
    return __builtin_amdgcn_mfma_f32_16x16x32_f16(a, b, c, 0, 0, 0);
}

// Async global->LDS, 16B per lane. LDS dest = wave-uniform base + lane*16.
__device__ __forceinline__ void gload16(const f16* g, f16* l) {
    __builtin_amdgcn_global_load_lds(
        (const __attribute__((address_space(1))) uint32_t*)g,
        (__attribute__((address_space(3))) uint32_t*)l, 16, 0, 0);
}

// ---------------------------------------------------------------------------
// GEMM: C[m][n] = sum_k A[m*1024+k]*B[n*1024+k] + bias. K=1024, A/B f16 stride
// 1024. 128x128 tile, 4 waves 2x2, 16x16x32 f16 MFMA. global_load_lds staging
// with XOR chunk swizzle folded into the per-lane SOURCE address: LDS chunk
// slot c' of row r holds global chunk c' ^ (r&7) -> conflict-light b128 reads.
// ---------------------------------------------------------------------------
template <bool OUT16, bool BIASROW, bool XN>
__global__ __launch_bounds__(256, 2) void gemm128h(const f16* __restrict__ A,
                                                   const f16* __restrict__ B,
                                                   const float* __restrict__ bias,
                                                   void* __restrict__ Cout, long ldo) {
    __shared__ __align__(16) f16 As[128 * 64];
    __shared__ __align__(16) f16 Bs[128 * 64];
    int tid = threadIdx.x;
    int lane = tid & 63, w = tid >> 6;
    int wm = w & 1, wn = w >> 1;
    int l15 = lane & 15, quad = lane >> 4;
    long m0 = (long)(XN ? blockIdx.y : blockIdx.x) * 128;
    long n0 = (long)(XN ? blockIdx.x : blockIdx.y) * 128;

    int rg = lane >> 3;        // row within 8-row staging group
    int cg = (lane & 7) ^ rg;  // global chunk index (swizzled)
    const f16* ag[4];
    const f16* bg[4];
    f16* al[4];
    f16* bl[4];
#pragma unroll
    for (int t = 0; t < 4; ++t) {
        int rb = (w * 4 + t) * 8;
        ag[t] = A + (m0 + rb + rg) * 1024 + cg * 8;
        bg[t] = B + (n0 + rb + rg) * 1024 + cg * 8;
        al[t] = &As[rb * 64];
        bl[t] = &Bs[rb * 64];
    }

    f32x4 acc[4][4] = {};

    for (int k0 = 0; k0 < 1024; k0 += 64) {
        __syncthreads();
#pragma unroll
        for (int t = 0; t < 4; ++t) {
            gload16(ag[t] + k0, al[t]);
            gload16(bg[t] + k0, bl[t]);
        }
        __syncthreads();  // drains vmcnt -> tiles resident
#pragma unroll
        for (int ks = 0; ks < 2; ++ks) {
            int cc = (ks * 4 + quad) ^ (l15 & 7);
            f16x8 af[4], bf[4];
#pragma unroll
            for (int t = 0; t < 4; ++t) {
                af[t] = *(const f16x8*)&As[(wm * 64 + t * 16 + l15) * 64 + cc * 8];
                bf[t] = *(const f16x8*)&Bs[(wn * 64 + t * 16 + l15) * 64 + cc * 8];
            }
#pragma unroll
            for (int i = 0; i < 4; ++i)
#pragma unroll
                for (int j = 0; j < 4; ++j)
                    acc[i][j] = mfma16(af[i], bf[j], acc[i][j]);
        }
    }

    // C/D layout: col = lane&15, row = quad*4 + reg
#pragma unroll
    for (int i = 0; i < 4; ++i) {
        int mrow = wm * 64 + i * 16 + quad * 4;
#pragma unroll
        for (int j = 0; j < 4; ++j) {
            int ncol = wn * 64 + j * 16 + l15;
            long gn = n0 + ncol;
#pragma unroll
            for (int r = 0; r < 4; ++r) {
                long gm = m0 + mrow + r;
                float v = acc[i][j][r] + (BIASROW ? bias[gm] : bias[gn]);
                if constexpr (OUT16)
                    ((f16*)Cout)[gm * ldo + gn] = (f16)v;
                else
                    ((float*)Cout)[gm * ldo + gn] = v;
            }
        }
    }
}

// ---------------------------------------------------------------------------
// Attention: one block per (n, h, 128-q-tile); 32 k-tiles of 64. Unnormalized
// accumulation (logits bounded), divide by rowsum at end. K/V double-buffered
// via global_load_lds prefetch issued between S-MFMA and exp/pack. Grid is
// XCD-swizzled: all 16 q-tiles of one (n,h) -> one XCD (K/V stay in its L2).
// ---------------------------------------------------------------------------
__global__ __launch_bounds__(256, 2) void attn128(const f16* __restrict__ Qp,
                                                  const f16* __restrict__ Kp,
                                                  const f16* __restrict__ Vt,
                                                  f16* __restrict__ Op) {
    __shared__ __align__(16) f16 Qs[128 * 64];
    __shared__ __align__(16) f16 Ks[2][64 * 64];
    __shared__ __align__(16) f16 Vs[2][64 * 64];
    __shared__ __align__(16) f16 Ps[128 * 64];
    __shared__ float lsi[128];

    int tid = threadIdx.x;
    int lane = tid & 63, w = tid >> 6;
    int l15 = lane & 15, quad = lane >> 4;
    int b = blockIdx.x;
    int xcd = b & 7, slot = b >> 3;
    int nh = xcd * 8 + (slot >> 4);  // blocks of one (n,h) share an XCD
    int qt = slot & 15;
    int nb = nh >> 4, h = nh & 15;
    long tok0 = (long)nb * 2048;

    int rg = lane >> 3, cg = (lane & 7) ^ rg;

    // stage Q tile (16 instr total)
    const f16* qsrc = Qp + (tok0 + qt * 128) * 1024 + h * 64;
#pragma unroll
    for (int t = 0; t < 4; ++t) {
        int rb = w * 32 + t * 8;
        gload16(qsrc + (rb + rg) * 1024 + cg * 8, &Qs[rb * 64]);
    }
    // per-lane K/V source bases (kt = 0)
    const f16* kbase = Kp + (tok0 + w * 16 + rg) * 1024 + h * 64 + cg * 8;
    const f16* vbase = Vt + ((long)h * 64 + w * 16 + rg) * 8192 + tok0 + cg * 8;
#pragma unroll
    for (int t = 0; t < 2; ++t) {
        gload16(kbase + t * 8 * 1024, &Ks[0][(w * 16 + t * 8) * 64]);
        gload16(vbase + (long)t * 8 * 8192, &Vs[0][(w * 16 + t * 8) * 64]);
    }
    __syncthreads();

    // Q fragments are loop-invariant: hoist
    f16x8 qf[2][2];
#pragma unroll
    for (int ks = 0; ks < 2; ++ks) {
        int cc = (ks * 4 + quad) ^ (l15 & 7);
#pragma unroll
        for (int j = 0; j < 2; ++j)
            qf[ks][j] = *(const f16x8*)&Qs[(w * 32 + j * 16 + l15) * 64 + cc * 8];
    }

    f32x4 oacc[2][4] = {};
    float rsum[2] = {0.f, 0.f};

    for (int kt = 0; kt < 32; ++kt) {
        int cur = kt & 1;
        // S^T tile = K(64 rows) x Q^T; D[k][q], wave w owns q in [w*32, w*32+32)
        f32x4 sacc[4][2] = {};
#pragma unroll
        for (int ks = 0; ks < 2; ++ks) {
            int cc = (ks * 4 + quad) ^ (l15 & 7);
            f16x8 af[4];
#pragma unroll
            for (int t = 0; t < 4; ++t)
                af[t] = *(const f16x8*)&Ks[cur][(t * 16 + l15) * 64 + cc * 8];
#pragma unroll
            for (int i = 0; i < 4; ++i)
#pragma unroll
                for (int j = 0; j < 2; ++j)
                    sacc[i][j] = mfma16(af[i], qf[ks][j], sacc[i][j]);
        }
        // async prefetch of next K/V tile (overlaps exp/pack below)
        if (kt < 31) {
            int nxt = cur ^ 1;
            const f16* kp2 = kbase + (long)(kt + 1) * 65536;
            const f16* vp2 = vbase + (kt + 1) * 64;
#pragma unroll
            for (int t = 0; t < 2; ++t) {
                gload16(kp2 + t * 8 * 1024, &Ks[nxt][(w * 16 + t * 8) * 64]);
                gload16(vp2 + (long)t * 8 * 8192, &Vs[nxt][(w * 16 + t * 8) * 64]);
            }
        }
        // exp, rowsum, pack P into LDS (A-operand layout, swizzled)
#pragma unroll
        for (int i = 0; i < 4; ++i) {
#pragma unroll
            for (int j = 0; j < 2; ++j) {
                float p0 = __expf(sacc[i][j][0] * 0.03125f);
                float p1 = __expf(sacc[i][j][1] * 0.03125f);
                float p2 = __expf(sacc[i][j][2] * 0.03125f);
                float p3 = __expf(sacc[i][j][3] * 0.03125f);
                rsum[j] += (p0 + p1) + (p2 + p3);
                f16x2 lo = __builtin_bit_cast(f16x2, __builtin_amdgcn_cvt_pkrtz(p0, p1));
                f16x2 hi = __builtin_bit_cast(f16x2, __builtin_amdgcn_cvt_pkrtz(p2, p3));
                f16x4 ph;
                ph[0] = lo[0]; ph[1] = lo[1]; ph[2] = hi[0]; ph[3] = hi[1];
                int qrow = w * 32 + j * 16 + l15;
                int kl = i * 16 + quad * 4;
                int c = kl >> 3;
                *(f16x4*)&Ps[qrow * 64 + ((c ^ (qrow & 7)) << 3) + (kl & 7)] = ph;
            }
        }
        __syncthreads();
        // O += P(q,k) x V(d,k)^T
#pragma unroll
        for (int ks = 0; ks < 2; ++ks) {
            int cc = (ks * 4 + quad) ^ (l15 & 7);
            f16x8 af[2], bf[4];
#pragma unroll
            for (int i = 0; i < 2; ++i)
                af[i] = *(const f16x8*)&Ps[(w * 32 + i * 16 + l15) * 64 + cc * 8];
#pragma unroll
            for (int j = 0; j < 4; ++j)
                bf[j] = *(const f16x8*)&Vs[cur][(j * 16 + l15) * 64 + cc * 8];
#pragma unroll
            for (int i = 0; i < 2; ++i)
#pragma unroll
                for (int j = 0; j < 4; ++j)
                    oacc[i][j] = mfma16(af[i], bf[j], oacc[i][j]);
        }
        __syncthreads();
    }

    // rowsum reduction across quads (q lives in lanes l, l^16, l^32, l^48)
#pragma unroll
    for (int j = 0; j < 2; ++j) {
        rsum[j] += __shfl_xor(rsum[j], 16, 64);
        rsum[j] += __shfl_xor(rsum[j], 32, 64);
    }
    if (lane < 16) {
        lsi[w * 32 + lane] = 1.0f / rsum[0];
        lsi[w * 32 + 16 + lane] = 1.0f / rsum[1];
    }
    __syncthreads();

    long otok = tok0 + (long)qt * 128;
#pragma unroll
    for (int i = 0; i < 2; ++i) {
        int qrow = w * 32 + i * 16 + quad * 4;
#pragma unroll
        for (int j = 0; j < 4; ++j) {
            int d = j * 16 + l15;
#pragma unroll
            for (int r = 0; r < 4; ++r) {
                float v = oacc[i][j][r] * lsi[qrow + r];
                Op[(otok + qrow + r) * 1024 + h * 64 + d] = (f16)v;
            }
        }
    }
}

// Fused fp32->fp16 conversion: q,k,v (8.4M elems each) + 4 weights (1M each).
// 8 elements per thread, RNE casts.
__global__ void cvt_all(const float* __restrict__ q, const float* __restrict__ k,
                        const float* __restrict__ v, const float* __restrict__ w0,
                        const float* __restrict__ w1, const float* __restrict__ w2,
                        const float* __restrict__ w3, f16* __restrict__ qh,
                        f16* __restrict__ kh, f16* __restrict__ vh,
                        f16* __restrict__ wh) {
    long id = (long)blockIdx.x * 256 + threadIdx.x;  // 3,670,016 total
    const float* s;
    f16* d;
    long off;
    if (id < 3145728) {
        int which = (int)(id >> 20);
        off = (id & 1048575) * 8;
        s = which == 0 ? q : which == 1 ? k : v;
        d = which == 0 ? qh : which == 1 ? kh : vh;
    } else {
        long id2 = id - 3145728;
        int wi = (int)(id2 >> 17);
        off = (id2 & 131071) * 8;
        s = wi == 0 ? w0 : wi == 1 ? w1 : wi == 2 ? w2 : w3;
        d = wh + (long)wi * 1048576;
    }
    f32x4 a = *(const f32x4*)(s + off);
    f32x4 b = *(const f32x4*)(s + off + 4);
    f16x8 hv;
    hv[0] = (f16)a[0]; hv[1] = (f16)a[1]; hv[2] = (f16)a[2]; hv[3] = (f16)a[3];
    hv[4] = (f16)b[0]; hv[5] = (f16)b[1]; hv[6] = (f16)b[2]; hv[7] = (f16)b[3];
    *(f16x8*)(d + off) = hv;
}

extern "C" void kernel_launch(void* const* d_in, const int* in_sizes, int n_in,
                              void* d_out, int out_size, void* d_ws, size_t ws_size,
                              hipStream_t stream) {
    const float* q  = (const float*)d_in[0];
    const float* k  = (const float*)d_in[1];
    const float* v  = (const float*)d_in[2];
    // d_in[3] padding_mask, d_in[4] sequence_mask: no effect in reference
    const float* Wq = (const float*)d_in[5];
    const float* bq = (const float*)d_in[6];
    const float* Wk = (const float*)d_in[7];
    const float* bk = (const float*)d_in[8];
    const float* Wv = (const float*)d_in[9];
    const float* bv = (const float*)d_in[10];
    const float* Wo = (const float*)d_in[11];
    const float* bo = (const float*)d_in[12];

    // 72 MB workspace with lifetime-based aliasing (stream-serial order):
    //   X  [ 0,16MB): vh (cvt..gemmV), then Op (attn..gemmO)
    //   Wh [16,24MB): Wq,Wk,Wv,Wo f16
    //   Qp [24,40MB)
    //   Kp [40,56MB): qh (cvt..gemmQ), then Kp (gemmK..attn)
    //   Vt [56,72MB): kh (cvt..gemmK), then Vt (gemmV..attn)
    char* ws = (char*)d_ws;
    f16* X  = (f16*)ws;
    f16* Wh = (f16*)(ws + (16L << 20));
    f16* Qp = (f16*)(ws + (24L << 20));
    f16* Kp = (f16*)(ws + (40L << 20));
    f16* Vt = (f16*)(ws + (56L << 20));
    f16* qh = Kp;
    f16* kh = Vt;
    f16* vh = X;
    f16* Op = X;

    cvt_all<<<14336, 256, 0, stream>>>(q, k, v, Wq, Wk, Wv, Wo, qh, kh, vh, Wh);

    // Qp = q@Wq^T+bq ; Kp = k@Wk^T+bk   (x = m-block: A-rows shared on one XCD)
    gemm128h<true, false, false><<<dim3(64, 8), 256, 0, stream>>>(qh, Wh, bq, Qp, 1024);
    gemm128h<true, false, false><<<dim3(64, 8), 256, 0, stream>>>(kh, Wh + 1048576, bk, Kp, 1024);
    // Vt = (v@Wv^T+bv)^T = Wv x v^T -> [e][tok]; x = n-block (B-rows share XCD)
    gemm128h<true, true, true><<<dim3(64, 8), 256, 0, stream>>>(Wh + 2097152, vh, bv, Vt, 8192);

    attn128<<<1024, 256, 0, stream>>>(Qp, Kp, Vt, Op);

    // out = Op@Wo^T + bo (fp32)
    gemm128h<false, false, false><<<dim3(64, 8), 256, 0, stream>>>(Op, Wh + 3145728, bo, (float*)d_out, 1024);
}